// Round 6
// baseline (270.666 us; speedup 1.0000x reference)
//
#include <hip/hip_runtime.h>

#define FDIM 64

typedef unsigned short u16;
typedef unsigned int u32;
typedef float v2f __attribute__((ext_vector_type(2)));

// pack 4 f32 -> 4 fp8 e4m3 (OCP on gfx950) in one u32
__device__ __forceinline__ u32 pk_fp8x4(float a, float b, float c, float d) {
    u32 p = __builtin_amdgcn_cvt_pk_fp8_f32(a, b, 0, false);
    p = __builtin_amdgcn_cvt_pk_fp8_f32(c, d, p, true);
    return p;
}

// ========= mm compute phase: t[64 rows] = As @ Ws (fp8 out) =========
// SCALE: multiply output row R by rsqrt(cnt[R]+1) before fp8 pack.

template <bool SCALE>
__device__ __forceinline__ void mm_compute(
    u32* __restrict__ t, const int* __restrict__ cnt, int n, int r0,
    float (*__restrict__ As)[FDIM + 1], const float* __restrict__ Ws)
{
    int tid = threadIdx.x;
    int rq = tid >> 4;   // rows rq*4..+3
    int cq = tid & 15;   // cols cq*4..+3
    float acc[4][4];
    #pragma unroll
    for (int i = 0; i < 4; ++i)
        #pragma unroll
        for (int j = 0; j < 4; ++j) acc[i][j] = 0.f;

    const float4* Ws4 = (const float4*)Ws;
    #pragma unroll 4
    for (int k = 0; k < FDIM; ++k) {
        float4 w = Ws4[k * 16 + cq];
        float a[4];
        #pragma unroll
        for (int i = 0; i < 4; ++i) a[i] = As[rq * 4 + i][k];
        #pragma unroll
        for (int i = 0; i < 4; ++i) {
            acc[i][0] = fmaf(a[i], w.x, acc[i][0]);
            acc[i][1] = fmaf(a[i], w.y, acc[i][1]);
            acc[i][2] = fmaf(a[i], w.z, acc[i][2]);
            acc[i][3] = fmaf(a[i], w.w, acc[i][3]);
        }
    }

    #pragma unroll
    for (int i = 0; i < 4; ++i) {
        int R = r0 + rq * 4 + i;
        if (R < n) {
            float sc = 1.0f;
            if (SCALE) sc = rsqrtf((float)cnt[R] + 1.0f);
            t[(size_t)R * 16 + cq] =
                pk_fp8x4(acc[i][0] * sc, acc[i][1] * sc,
                         acc[i][2] * sc, acc[i][3] * sc);
        }
    }
}

// ===== combined dispatch: CSR-fill blocks (first) + matmul1 blocks =========
// Fill: partitioned grid-stride, 8 independent atomic chains in flight.
// (Proven insensitive to wave count / depth / counter padding.)

__global__ __launch_bounds__(256) void k_mm_fill(
    const float* __restrict__ x, const float* __restrict__ W1,
    u32* __restrict__ t,
    const int* __restrict__ src, const int* __restrict__ dst,
    int* __restrict__ cnt, int* __restrict__ csr,
    int n, int E, int cap, int fill_blocks)
{
    __shared__ float As[64][FDIM + 1];
    __shared__ float Ws[FDIM * FDIM];

    if ((int)blockIdx.x < fill_blocks) {
        int stride = fill_blocks * 256;
        int e = blockIdx.x * 256 + threadIdx.x;
        for (; e + 7 * stride < E; e += 8 * stride) {
            int d[8], s[8], p[8];
            #pragma unroll
            for (int u = 0; u < 8; ++u)
                d[u] = __builtin_nontemporal_load(&dst[e + u * stride]);
            #pragma unroll
            for (int u = 0; u < 8; ++u)
                s[u] = __builtin_nontemporal_load(&src[e + u * stride]);
            #pragma unroll
            for (int u = 0; u < 8; ++u) p[u] = atomicAdd(&cnt[d[u]], 1);
            #pragma unroll
            for (int u = 0; u < 8; ++u)
                if (p[u] < cap) csr[(size_t)d[u] * cap + p[u]] = s[u];
        }
        for (; e < E; e += stride) {
            int d = dst[e];
            int p = atomicAdd(&cnt[d], 1);
            if (p < cap) csr[(size_t)d * cap + p] = src[e];
        }
        return;
    }

    int blk = blockIdx.x - fill_blocks;
    int r0 = blk * 64;
    int tid = threadIdx.x;
    #pragma unroll
    for (int i = 0; i < 4; ++i)
        ((float4*)Ws)[tid + 256 * i] = ((const float4*)W1)[tid + 256 * i];

    // stage x rows (f32, no bias, no relu)
    #pragma unroll
    for (int i = 0; i < 4; ++i) {
        int idx = tid + 256 * i;
        int r = idx >> 4;
        int kq = idx & 15;
        float4 v = make_float4(0.f, 0.f, 0.f, 0.f);
        int R = r0 + r;
        if (R < n) v = ((const float4*)x)[(size_t)R * 16 + kq];
        As[r][kq * 4 + 0] = v.x;
        As[r][kq * 4 + 1] = v.y;
        As[r][kq * 4 + 2] = v.z;
        As[r][kq * 4 + 3] = v.w;
    }
    __syncthreads();
    mm_compute<false>(t, nullptr, n, r0, As, Ws);
}

// ===== gather batch: 16 unconditional loads (sv=-1 -> zero row) ===========
// One vmcnt wait per batch; full MLP. BUF must be a named local array
// (static indexing only -- runtime-indexed ext arrays go to scratch).

#define GATH(T, SVV, BUF) do {                                             \
    _Pragma("unroll")                                                      \
    for (int u_ = 0; u_ < 16; ++u_) {                                      \
        int jv_ = __shfl((SVV), nbase + u_);                               \
        BUF[u_] = (T)[(long long)jv_ * 16 + li];                           \
    } } while (0)

// == fused aggregate + matmul, SOFTWARE-PIPELINED ==
// Phase 1 preloads all 4 nodes' contexts (deg, self row, csr chunk,
// cnt[sv]); then gathers for node r+1 are issued before consuming node r
// (vb0/vb1 double buffer, hand-unrolled so all indices are static).
// deg>16 tail keeps the serial path (rare, ~3% of nodes at avg deg 10).

template <bool SCALED_IN>
__global__ __launch_bounds__(256) void k_aggmm(
    const int* __restrict__ cnt, const int* __restrict__ csr,
    const u32* __restrict__ tin, const float* __restrict__ Wm,
    const float* __restrict__ bias, u32* __restrict__ tout,
    int n, int cap)
{
    __shared__ float As[64][FDIM + 1];
    __shared__ float Ws[FDIM * FDIM];
    int tid = threadIdx.x;
    #pragma unroll
    for (int i = 0; i < 4; ++i)
        ((float4*)Ws)[tid + 256 * i] = ((const float4*)Wm)[tid + 256 * i];

    int r0 = blockIdx.x * 64;
    int group = tid >> 4;          // 0..15
    int li = tid & 15;
    int nbase = ((tid & 63) >> 4) << 4;
    float4 b = ((const float4*)bias)[li];

    // ---- phase 1: preload per-node context for the 4 nodes (independent)
    int mN[4]; float diN[4]; int svN[4]; int cvN[4]; u32 spN[4];
    #pragma unroll
    for (int r = 0; r < 4; ++r) {
        int i = r0 + r * 16 + group;
        bool ok = i < n;
        int ic = ok ? i : 0;
        int dg = cnt[ic];
        diN[r] = rsqrtf((float)dg + 1.0f);
        int m = ok ? (dg < cap ? dg : cap) : 0;
        mN[r] = m;
        spN[r] = tin[(long long)(ok ? i : -1) * 16 + li];   // zero row if !ok
        int cm = m < 16 ? m : 16;
        int sv = -1;
        if (li < cm) sv = __builtin_nontemporal_load(&csr[(size_t)ic * cap + li]);
        svN[r] = sv;
        cvN[r] = 0;
        if (!SCALED_IN && li < cm) cvN[r] = cnt[sv];
    }

    u32 vb0[16], vb1[16];

#define CONSUME_MM(R, BUF) do {                                            \
    int m_ = mN[R]; float di_ = diN[R];                                    \
    v2f s0_ = __builtin_amdgcn_cvt_pk_f32_fp8(spN[R], false);              \
    v2f s1_ = __builtin_amdgcn_cvt_pk_f32_fp8(spN[R], true);               \
    float4 A0, A1, A2, A3;                                                 \
    if (SCALED_IN) A0 = make_float4(s0_.x, s0_.y, s1_.x, s1_.y);           \
    else A0 = make_float4(s0_.x * di_, s0_.y * di_, s1_.x * di_, s1_.y * di_); \
    A1 = make_float4(0.f, 0.f, 0.f, 0.f); A2 = A1; A3 = A1;                \
    float dvv_ = SCALED_IN ? 0.f : rsqrtf((float)cvN[R] + 1.0f);           \
    _Pragma("unroll")                                                      \
    for (int u = 0; u < 16; ++u) {                                         \
        v2f x0 = __builtin_amdgcn_cvt_pk_f32_fp8(BUF[u], false);           \
        v2f x1 = __builtin_amdgcn_cvt_pk_f32_fp8(BUF[u], true);            \
        float4* Ap = (u & 3) == 0 ? &A0 : (u & 3) == 1 ? &A1 :             \
                     (u & 3) == 2 ? &A2 : &A3;                             \
        if (SCALED_IN) {                                                   \
            Ap->x += x0.x; Ap->y += x0.y; Ap->z += x1.x; Ap->w += x1.y;    \
        } else {                                                           \
            float dj_ = __shfl(dvv_, nbase + u);                           \
            Ap->x = fmaf(x0.x, dj_, Ap->x); Ap->y = fmaf(x0.y, dj_, Ap->y);\
            Ap->z = fmaf(x1.x, dj_, Ap->z); Ap->w = fmaf(x1.y, dj_, Ap->w);\
        }                                                                  \
    }                                                                      \
    if (m_ > 16) {      /* rare tail: serial chunks, reuse BUF */          \
        const int* row_ = csr + (size_t)(r0 + (R) * 16 + group) * cap;     \
        for (int c0 = 16; c0 < m_; c0 += 16) {                             \
            int cm2 = m_ - c0; if (cm2 > 16) cm2 = 16;                     \
            int sv2 = -1; float dv2 = 0.f;                                 \
            if (li < cm2) {                                                \
                sv2 = __builtin_nontemporal_load(&row_[c0 + li]);          \
                if (!SCALED_IN) dv2 = rsqrtf((float)cnt[sv2] + 1.0f);      \
            }                                                              \
            GATH(tin, sv2, BUF);                                           \
            _Pragma("unroll")                                              \
            for (int u = 0; u < 16; ++u) {                                 \
                v2f x0 = __builtin_amdgcn_cvt_pk_f32_fp8(BUF[u], false);   \
                v2f x1 = __builtin_amdgcn_cvt_pk_f32_fp8(BUF[u], true);    \
                float4* Ap = (u & 3) == 0 ? &A0 : (u & 3) == 1 ? &A1 :     \
                             (u & 3) == 2 ? &A2 : &A3;                     \
                if (SCALED_IN) {                                           \
                    Ap->x += x0.x; Ap->y += x0.y;                          \
                    Ap->z += x1.x; Ap->w += x1.y;                          \
                } else {                                                   \
                    float dj2 = __shfl(dv2, nbase + u);                    \
                    Ap->x = fmaf(x0.x, dj2, Ap->x);                        \
                    Ap->y = fmaf(x0.y, dj2, Ap->y);                        \
                    Ap->z = fmaf(x1.x, dj2, Ap->z);                        \
                    Ap->w = fmaf(x1.y, dj2, Ap->w);                        \
                }                                                          \
            }                                                              \
        }                                                                  \
    }                                                                      \
    float4 O_;                                                             \
    O_.x = ((A0.x + A1.x) + (A2.x + A3.x)) * di_;                          \
    O_.y = ((A0.y + A1.y) + (A2.y + A3.y)) * di_;                          \
    O_.z = ((A0.z + A1.z) + (A2.z + A3.z)) * di_;                          \
    O_.w = ((A0.w + A1.w) + (A2.w + A3.w)) * di_;                          \
    int row2_ = (R) * 16 + group;                                          \
    As[row2_][li * 4 + 0] = fmaxf(O_.x + b.x, 0.f);                        \
    As[row2_][li * 4 + 1] = fmaxf(O_.y + b.y, 0.f);                        \
    As[row2_][li * 4 + 2] = fmaxf(O_.z + b.z, 0.f);                        \
    As[row2_][li * 4 + 3] = fmaxf(O_.w + b.w, 0.f);                        \
} while (0)

    // pipelined schedule: gathers for node r+1 in flight while consuming r
    GATH(tin, svN[0], vb0);
    GATH(tin, svN[1], vb1);
    CONSUME_MM(0, vb0);
    GATH(tin, svN[2], vb0);
    CONSUME_MM(1, vb1);
    GATH(tin, svN[3], vb1);
    CONSUME_MM(2, vb0);
    CONSUME_MM(3, vb1);
#undef CONSUME_MM

    __syncthreads();
    mm_compute<true>(tout, cnt, n, r0, As, Ws);
}

// == layer-3 aggregate + pool partial-sum, 3-stage pipelined ==
// stages: ctx(i+2S) load || gathers(i+S) issue || consume(i).
// Out-of-range nodes are dummy-guarded (m=0, di=0, sv=-1 -> zero rows,
// contribution exactly 0) so the two-half loop needs no edge branches.
// NO fences here (round 3/4 lesson: per-block device fences cost ~90us).

__global__ __launch_bounds__(256) void k_agg_pool(
    const int* __restrict__ cnt, const int* __restrict__ csr,
    const u32* __restrict__ t, const int* __restrict__ batch,
    float* __restrict__ partial, int n, int cap, int npart)
{
    int g = blockIdx.x / npart;
    int part = blockIdx.x - g * npart;
    int tid = threadIdx.x;

    int lo = 0, hi = n;
    while (lo < hi) { int mid = (lo + hi) >> 1; if (batch[mid] < g) lo = mid + 1; else hi = mid; }
    int start = lo;
    hi = n;
    while (lo < hi) { int mid = (lo + hi) >> 1; if (batch[mid] <= g) lo = mid + 1; else hi = mid; }
    int end = lo;

    int group = tid >> 4;     // 0..15
    int li = tid & 15;
    int nbase = ((tid & 63) >> 4) << 4;

#define LCTX(II, M, DI, SV, SP) do {                                       \
    (M) = 0; (DI) = 0.f; (SV) = -1; (SP) = 0u;                             \
    if ((II) < end) {                                                      \
        int dg_ = cnt[(II)];                                               \
        (DI) = rsqrtf((float)dg_ + 1.0f);                                  \
        (M) = dg_ < cap ? dg_ : cap;                                       \
        (SP) = t[(size_t)(II) * 16 + li];                                  \
        int cm_ = (M) < 16 ? (M) : 16;                                     \
        if (li < cm_) (SV) = __builtin_nontemporal_load(                   \
                                 &csr[(size_t)(II) * cap + li]);           \
    } } while (0)

#define CONSUME_P(M_, DI_, SP_, II_, BUF) do {                             \
    v2f s0_ = __builtin_amdgcn_cvt_pk_f32_fp8((SP_), false);               \
    v2f s1_ = __builtin_amdgcn_cvt_pk_f32_fp8((SP_), true);                \
    float4 A0 = make_float4(s0_.x, s0_.y, s1_.x, s1_.y);                   \
    float4 A1 = make_float4(0.f, 0.f, 0.f, 0.f), A2 = A1, A3 = A1;         \
    _Pragma("unroll")                                                      \
    for (int u = 0; u < 16; ++u) {                                         \
        v2f x0 = __builtin_amdgcn_cvt_pk_f32_fp8(BUF[u], false);           \
        v2f x1 = __builtin_amdgcn_cvt_pk_f32_fp8(BUF[u], true);            \
        float4* Ap = (u & 3) == 0 ? &A0 : (u & 3) == 1 ? &A1 :             \
                     (u & 3) == 2 ? &A2 : &A3;                             \
        Ap->x += x0.x; Ap->y += x0.y; Ap->z += x1.x; Ap->w += x1.y;        \
    }                                                                      \
    if ((M_) > 16) {                                                       \
        const int* row_ = csr + (size_t)(II_) * cap;                       \
        for (int c0 = 16; c0 < (M_); c0 += 16) {                           \
            int cm2 = (M_) - c0; if (cm2 > 16) cm2 = 16;                   \
            int sv2 = -1;                                                  \
            if (li < cm2) sv2 = __builtin_nontemporal_load(&row_[c0 + li]);\
            GATH(t, sv2, BUF);                                             \
            _Pragma("unroll")                                              \
            for (int u = 0; u < 16; ++u) {                                 \
                v2f x0 = __builtin_amdgcn_cvt_pk_f32_fp8(BUF[u], false);   \
                v2f x1 = __builtin_amdgcn_cvt_pk_f32_fp8(BUF[u], true);    \
                float4* Ap = (u & 3) == 0 ? &A0 : (u & 3) == 1 ? &A1 :     \
                             (u & 3) == 2 ? &A2 : &A3;                     \
                Ap->x += x0.x; Ap->y += x0.y; Ap->z += x1.x; Ap->w += x1.y;\
            }                                                              \
        }                                                                  \
    }                                                                      \
    acc.x += ((A0.x + A1.x) + (A2.x + A3.x)) * (DI_);                      \
    acc.y += ((A0.y + A1.y) + (A2.y + A3.y)) * (DI_);                      \
    acc.z += ((A0.z + A1.z) + (A2.z + A3.z)) * (DI_);                      \
    acc.w += ((A0.w + A1.w) + (A2.w + A3.w)) * (DI_);                      \
} while (0)

    const int S = npart * 16;
    float4 acc = make_float4(0.f, 0.f, 0.f, 0.f);
    int i = start + part * 16 + group;

    int mA, svA, iiA; float diA; u32 spA;
    int mB, svB, iiB; float diB; u32 spB;
    int mT, svT, iiT; float diT; u32 spT;
    u32 vb0[16], vb1[16];

    iiA = i;     LCTX(iiA, mA, diA, svA, spA);
    iiB = i + S; LCTX(iiB, mB, diB, svB, spB);
    GATH(t, svA, vb0);

    while (i < end) {
        GATH(t, svB, vb1);
        iiT = i + 2 * S; LCTX(iiT, mT, diT, svT, spT);
        CONSUME_P(mA, diA, spA, iiA, vb0);
        mA = mB; diA = diB; svA = svB; spA = spB; iiA = iiB;
        mB = mT; diB = diT; svB = svT; spB = spT; iiB = iiT;
        i += S;
        if (i >= end) break;

        GATH(t, svB, vb0);
        iiT = i + 2 * S; LCTX(iiT, mT, diT, svT, spT);
        CONSUME_P(mA, diA, spA, iiA, vb1);
        mA = mB; diA = diB; svA = svB; spA = spB; iiA = iiB;
        mB = mT; diB = diT; svB = svT; spB = spT; iiB = iiT;
        i += S;
    }
#undef CONSUME_P
#undef LCTX

    __shared__ float4 red[16][16];
    red[group][li] = acc;
    __syncthreads();
    if (tid < 16) {
        float4 s = make_float4(0.f, 0.f, 0.f, 0.f);
        #pragma unroll
        for (int q = 0; q < 16; ++q) {
            s.x += red[q][tid].x; s.y += red[q][tid].y;
            s.z += red[q][tid].z; s.w += red[q][tid].w;
        }
        ((float4*)partial)[((size_t)g * npart + part) * 16 + tid] = s;
    }
}

// == final: reduce partials + mean + b3 + Wlin + blin, one block/graph ==

__global__ __launch_bounds__(64) void k_pool2(
    const float* __restrict__ partial, const int* __restrict__ batch,
    const float* __restrict__ b3, const float* __restrict__ Wlin,
    const float* __restrict__ blin, float* __restrict__ out,
    int n, int fout, int npart)
{
    int g = blockIdx.x;
    int tid = threadIdx.x;

    int lo = 0, hi = n;
    while (lo < hi) { int mid = (lo + hi) >> 1; if (batch[mid] < g) lo = mid + 1; else hi = mid; }
    int start = lo;
    hi = n;
    while (lo < hi) { int mid = (lo + hi) >> 1; if (batch[mid] <= g) lo = mid + 1; else hi = mid; }
    int cg = lo - start;

    __shared__ float pooled[64];
    float v = 0.f;
    for (int p = 0; p < npart; ++p)
        v += partial[((size_t)g * npart + p) * 64 + tid];
    pooled[tid] = (cg > 0) ? (v / (float)cg + b3[tid]) : 0.f;
    __syncthreads();
    if (tid < fout) {
        float o = blin[tid];
        for (int k = 0; k < 64; ++k) o += pooled[k] * Wlin[k * fout + tid];
        out[(size_t)g * fout + tid] = o;
    }
}

// ================= launcher =================

extern "C" void kernel_launch(void* const* d_in, const int* in_sizes, int n_in,
                              void* d_out, int out_size, void* d_ws, size_t ws_size,
                              hipStream_t stream) {
    const float* x     = (const float*)d_in[0];
    const int*   ei    = (const int*)d_in[1];
    const int*   batch = (const int*)d_in[2];
    const float* W1 = (const float*)d_in[3];
    const float* b1 = (const float*)d_in[4];
    const float* W2 = (const float*)d_in[5];
    const float* b2 = (const float*)d_in[6];
    const float* W3 = (const float*)d_in[7];
    const float* b3 = (const float*)d_in[8];
    const float* Wl = (const float*)d_in[9];
    const float* bl = (const float*)d_in[10];

    int n = in_sizes[0] / 64;
    int E = in_sizes[1] / 2;
    int fout = in_sizes[10];
    int ngraphs = out_size / fout;

    const int* srcp = ei;
    const int* dstp = ei + E;

    const int npart = 32;   // 2048 agg_pool blocks -> 8 waves/SIMD demand

    // ws layout: cnt | zA (zero row) | tA | zB (zero row) | tB | partial | csr
    int* cnt = (int*)d_ws;                           // n
    u32* zA  = (u32*)(cnt + n);                      // 16 (zero row for tA)
    u32* tA  = zA + 16;                              // n*16
    u32* zB  = tA + (size_t)n * 16;                  // 16 (zero row for tB)
    u32* tB  = zB + 16;                              // n*16
    float* partial = (float*)(tB + (size_t)n * 16);  // ngraphs*npart*64
    int* csr = (int*)(partial + (size_t)ngraphs * npart * 64);

    size_t fixed = (size_t)n * 4 + 128 + (size_t)n * 128 +
                   (size_t)ngraphs * npart * 64 * 4;
    int cap = 64;
    while (cap > 32 && fixed + (size_t)n * cap * 4 > ws_size) cap -= 8;

    int mm_blocks = (n + 63) / 64;
    int fill_blocks = 256;

    // two small memsets (don't sweep 6.4MB of tA just to reach zB)
    hipMemsetAsync(cnt, 0, (size_t)n * 4 + 64, stream);   // cnt + zA
    hipMemsetAsync(zB, 0, 64, stream);                    // zB
    // CSR build + t1 = x @ W1 (fp8, unscaled), one dispatch
    k_mm_fill<<<fill_blocks + mm_blocks, 256, 0, stream>>>(
        x, W1, tA, srcp, dstp, cnt, csr, n, E, cap, fill_blocks);

    // layer1 agg (unscaled t1) + layer2 matmul -> t2 (pre-scaled)
    k_aggmm<false><<<mm_blocks, 256, 0, stream>>>(cnt, csr, tA, W2, b1, tB, n, cap);
    // layer2 agg (scaled t2) + layer3 matmul -> t3 (pre-scaled)
    k_aggmm<true><<<mm_blocks, 256, 0, stream>>>(cnt, csr, tB, W3, b2, tA, n, cap);
    // layer3 agg + pool partial-sum (pipelined, no fences)
    k_agg_pool<<<ngraphs * npart, 256, 0, stream>>>(
        cnt, csr, tA, batch, partial, n, cap, npart);
    // final reduce + linear
    k_pool2<<<ngraphs, 64, 0, stream>>>(partial, batch, b3, Wl, bl,
                                        (float*)d_out, n, fout, npart);
}